// Round 3
// baseline (451.330 us; speedup 1.0000x reference)
//
#include <hip/hip_runtime.h>
#include <hip/hip_cooperative_groups.h>
#include <stdint.h>
#include <math.h>

namespace cg = cooperative_groups;

#define HIST_BINS   65536
#define HIST_WORDS8 16384          // uint32 words, 4 packed uint8 bins each (64 KB LDS)
#define NBLK        256            // fused grid: 1 block per CU, residency guaranteed
#define NTHR        1024

// ---------- float <-> monotonic uint key (legacy fallback only) ----------
__device__ __forceinline__ uint32_t f2key(float f){
    uint32_t u = __float_as_uint(f);
    return (u & 0x80000000u) ? ~u : (u | 0x80000000u);
}
__device__ __forceinline__ float key2f(uint32_t k){
    uint32_t u = (k & 0x80000000u) ? (k ^ 0x80000000u) : ~k;
    return __uint_as_float(u);
}

__device__ __forceinline__ void mm4(float4 a, float& mn, float& mx){
    mn = fminf(mn, fminf(fminf(a.x, a.y), fminf(a.z, a.w)));
    mx = fmaxf(mx, fmaxf(fmaxf(a.x, a.y), fmaxf(a.z, a.w)));
}

__device__ __forceinline__ void bin_pair(float vx, float vy,
                                         float mnx, float sx, float mny, float sy,
                                         uint32_t* lh){
    int ix = (int)floorf((vx - mnx) * sx);
    int iy = (int)floorf((vy - mny) * sy);
    ix = ix < 0 ? 0 : (ix > 255 ? 255 : ix);
    iy = iy < 0 ? 0 : (iy > 255 ? 255 : iy);
    uint32_t bin = ((uint32_t)ix << 8) | (uint32_t)iy;
    atomicAdd(&lh[bin >> 2], 1u << ((bin & 3u) * 8u));
}

__device__ __forceinline__ void bin4(float4 a, float4 b,
                                     float mnx, float sx, float mny, float sy,
                                     uint32_t* lh){
    bin_pair(a.x, b.x, mnx, sx, mny, sy, lh);
    bin_pair(a.y, b.y, mnx, sx, mny, sy, lh);
    bin_pair(a.z, b.z, mnx, sx, mny, sy, lh);
    bin_pair(a.w, b.w, mnx, sx, mny, sy, lh);
}

__device__ double bsum1024(double v, double* red, int t){
    #pragma unroll
    for (int off = 32; off > 0; off >>= 1) v += __shfl_down(v, off, 64);
    __syncthreads();
    if ((t & 63) == 0) red[t >> 6] = v;
    __syncthreads();
    if (t == 0){
        double s = 0.0;
        for (int w = 0; w < 16; ++w) s += red[w];
        v = s;
    }
    return v;  // valid in thread 0 only
}

// Shared finalize body (all 1024 threads of the calling block participate).
__device__ void finalize_dev(const uint32_t* __restrict__ hist, float* __restrict__ out,
                             int n, uint32_t* rsum, uint32_t* csum4, uint32_t* csum,
                             double* red){
    int t = threadIdx.x;
    // Phase A: row sums. 4 threads per row, 16 uint4 (64 words) each, coalesced.
    {
        int r = t >> 2, q = t & 3;
        const uint4* hp = (const uint4*)(hist + r * 256 + q * 64);
        uint32_t s = 0;
        #pragma unroll
        for (int k = 0; k < 16; ++k){
            uint4 v = hp[k];
            s += v.x + v.y + v.z + v.w;
        }
        s += __shfl_down(s, 2, 64);
        s += __shfl_down(s, 1, 64);
        if (q == 0) rsum[r] = s;
    }
    // Phase B: col sums. c = t&255 (coalesced across lanes), 4 row-groups.
    {
        int c = t & 255, g = t >> 8;
        const uint32_t* hp = hist + g * 64 * 256 + c;
        uint32_t s = 0;
        #pragma unroll 8
        for (int r = 0; r < 64; ++r) s += hp[r * 256];
        csum4[g * 256 + c] = s;
    }
    __syncthreads();
    if (t < 256) csum[t] = csum4[t] + csum4[256 + t] + csum4[512 + t] + csum4[768 + t];
    __syncthreads();

    const double invn = 1.0 / (double)n;
    const double dn = (double)n;
    double mi = 0.0;
    {
        int c = t & 255, rb = t >> 8;
        double cs = (double)csum[c];
        for (int k = 0; k < 64; ++k){
            int r = k * 4 + rb;
            uint32_t cnt = hist[r * 256 + c];
            if (cnt){
                double rs = (double)rsum[r];
                double ratio = ((double)cnt * dn) / (rs * cs);
                mi += (double)cnt * (double)logf((float)ratio);
            }
        }
        mi *= invn;
    }
    double hx = 0.0, hy = 0.0;
    if (t < 256){
        double px = (double)rsum[t] * invn;
        double py = (double)csum[t] * invn;
        hx = px * log(px + 1e-8);
        hy = py * log(py + 1e-8);
    }
    double mi_s = bsum1024(mi, red, t);
    double hx_s = bsum1024(hx, red, t);
    double hy_s = bsum1024(hy, red, t);
    if (t == 0){
        double h_x = -hx_s, h_y = -hy_s;
        double nmi = mi_s / (sqrt(h_x * h_y) + 1e-8);
        out[0] = (float)(-nmi);
    }
}

// ===================== fused cooperative kernel =====================
// ws layout (uint32 words):
//   [0 .. 65535]            final uint32 joint histogram (256 KB)
//   [65536 .. 66559]        per-block minmax float4 {mn_x, mx_x, mn_y, mx_y} (4 KB)
//   [66560 ...]             256 packed-uint8 partial histograms (16 MB)
__global__ void __launch_bounds__(NTHR, 4)
fused_kernel(const float4* __restrict__ x, const float4* __restrict__ y,
             uint32_t* __restrict__ ws, float* __restrict__ out, int n, int n4){
    union SM {
        uint32_t lh[HIST_WORDS8];       // 64 KB packed-uint8 local histogram
        uint32_t sm[64][16][16];        // 64 KB reduce staging
        struct {
            uint32_t rsum[256];
            uint32_t csum4[1024];
            uint32_t csum[256];
            double   red[16];
        } fin;                          // 6.3 KB finalize
    };
    __shared__ SM s;
    __shared__ float sxn[16], sxx[16], syn[16], syx[16];
    __shared__ float scale_sh[4];

    uint32_t* hist     = ws;
    float*    blockmm  = (float*)(ws + HIST_BINS);
    uint32_t* partials = ws + HIST_BINS + 1024;

    cg::grid_group grid = cg::this_grid();
    int t   = threadIdx.x;
    int bid = blockIdx.x;
    int seg   = (n4 + NBLK - 1) / NBLK;     // 32768 for n4 = 8.39M
    int start = bid * seg;
    int end   = start + seg; if (end > n4) end = n4;

    // ---- phase 1: per-block minmax of this block's x/y segments ----
    float mnx = INFINITY, mxx = -INFINITY, mny = INFINITY, mxy = -INFINITY;
    for (int i = start + t; i < end; i += NTHR){
        float4 a = x[i], b = y[i];
        mm4(a, mnx, mxx);
        mm4(b, mny, mxy);
    }
    #pragma unroll
    for (int off = 32; off > 0; off >>= 1){
        mnx = fminf(mnx, __shfl_down(mnx, off, 64));
        mxx = fmaxf(mxx, __shfl_down(mxx, off, 64));
        mny = fminf(mny, __shfl_down(mny, off, 64));
        mxy = fmaxf(mxy, __shfl_down(mxy, off, 64));
    }
    if ((t & 63) == 0){
        int w = t >> 6;
        sxn[w] = mnx; sxx[w] = mxx; syn[w] = mny; syx[w] = mxy;
    }
    __syncthreads();
    if (t == 0){
        for (int w = 1; w < 16; ++w){
            mnx = fminf(mnx, sxn[w]); mxx = fmaxf(mxx, sxx[w]);
            mny = fminf(mny, syn[w]); mxy = fmaxf(mxy, syx[w]);
        }
        ((float4*)blockmm)[bid] = make_float4(mnx, mxx, mny, mxy);
    }
    grid.sync();

    // ---- phase 2: zero LDS hist + compute global scale (no atomics, no init) ----
    for (int w = t; w < HIST_WORDS8; w += NTHR) s.lh[w] = 0u;
    if (t < NBLK){
        float4 m = ((const float4*)blockmm)[t];
        float a = m.x, b = m.y, c = m.z, d = m.w;
        #pragma unroll
        for (int off = 32; off > 0; off >>= 1){
            a = fminf(a, __shfl_down(a, off, 64));
            b = fmaxf(b, __shfl_down(b, off, 64));
            c = fminf(c, __shfl_down(c, off, 64));
            d = fmaxf(d, __shfl_down(d, off, 64));
        }
        if ((t & 63) == 0){
            int w = t >> 6;
            sxn[w] = a; sxx[w] = b; syn[w] = c; syx[w] = d;
        }
    }
    __syncthreads();
    if (t == 0){
        float a = sxn[0], b = sxx[0], c = syn[0], d = syx[0];
        for (int w = 1; w < 4; ++w){
            a = fminf(a, sxn[w]); b = fmaxf(b, sxx[w]);
            c = fminf(c, syn[w]); d = fmaxf(d, syx[w]);
        }
        scale_sh[0] = a;
        scale_sh[1] = 256.0f / ((b - a) + 1e-8f);
        scale_sh[2] = c;
        scale_sh[3] = 256.0f / ((d - c) + 1e-8f);
    }
    __syncthreads();

    // ---- phase 3: LDS histogram over this block's segment ----
    {
        float gmnx = scale_sh[0], gsx = scale_sh[1];
        float gmny = scale_sh[2], gsy = scale_sh[3];
        int base = start;
        for (; base + 4 * NTHR <= end; base += 4 * NTHR){
            int i0 = base + t;
            float4 a0 = x[i0], a1 = x[i0 + NTHR], a2 = x[i0 + 2*NTHR], a3 = x[i0 + 3*NTHR];
            float4 b0 = y[i0], b1 = y[i0 + NTHR], b2 = y[i0 + 2*NTHR], b3 = y[i0 + 3*NTHR];
            bin4(a0, b0, gmnx, gsx, gmny, gsy, s.lh);
            bin4(a1, b1, gmnx, gsx, gmny, gsy, s.lh);
            bin4(a2, b2, gmnx, gsx, gmny, gsy, s.lh);
            bin4(a3, b3, gmnx, gsx, gmny, gsy, s.lh);
        }
        for (int i = base + t; i < end; i += NTHR){
            float4 a = x[i], b = y[i];
            bin4(a, b, gmnx, gsx, gmny, gsy, s.lh);
        }
    }
    __syncthreads();
    {
        uint32_t* part = partials + (size_t)bid * HIST_WORDS8;
        for (int w = t; w < HIST_WORDS8; w += NTHR) part[w] = s.lh[w];
    }
    grid.sync();

    // ---- phase 4: distributed reduce (block b owns word-quads [b*16, b*16+16)) ----
    {
        int ql = t & 15, g = t >> 4;          // 64 groups of 4 partials each
        uint32_t c[16];
        #pragma unroll
        for (int k = 0; k < 16; ++k) c[k] = 0;
        const uint4* basep = (const uint4*)partials;
        size_t qoff = (size_t)bid * 16 + ql;
        #pragma unroll
        for (int j = 0; j < 4; ++j){
            uint4 v = basep[(size_t)(g * 4 + j) * (HIST_WORDS8 / 4) + qoff];
            c[ 0] += v.x & 255u; c[ 1] += (v.x >> 8) & 255u; c[ 2] += (v.x >> 16) & 255u; c[ 3] += v.x >> 24;
            c[ 4] += v.y & 255u; c[ 5] += (v.y >> 8) & 255u; c[ 6] += (v.y >> 16) & 255u; c[ 7] += v.y >> 24;
            c[ 8] += v.z & 255u; c[ 9] += (v.z >> 8) & 255u; c[10] += (v.z >> 16) & 255u; c[11] += v.z >> 24;
            c[12] += v.w & 255u; c[13] += (v.w >> 8) & 255u; c[14] += (v.w >> 16) & 255u; c[15] += v.w >> 24;
        }
        #pragma unroll
        for (int k = 0; k < 16; ++k) s.sm[g][k][ql] = c[k];
        __syncthreads();
        if (t < 256){
            int q2 = t & 15, k = t >> 4;
            uint32_t sum = 0;
            #pragma unroll 8
            for (int gg = 0; gg < 64; ++gg) sum += s.sm[gg][k][q2];
            hist[((size_t)bid * 16 + q2) * 16 + k] = sum;
        }
    }
    grid.sync();

    // ---- phase 5: finalize on block 0 ----
    if (bid == 0)
        finalize_dev(hist, out, n, s.fin.rsum, s.fin.csum4, s.fin.csum, s.fin.red);
}

// ===================== legacy fallback (small workspace) =====================
__global__ void init_mm_kernel(uint32_t* __restrict__ mm){
    mm[0] = 0xFFFFFFFFu; mm[1] = 0u; mm[2] = 0xFFFFFFFFu; mm[3] = 0u;
}

__global__ void __launch_bounds__(1024)
minmax_legacy(const float4* __restrict__ x, const float4* __restrict__ y,
              uint32_t* __restrict__ mm, int n4){
    __shared__ float sxn[16], sxx[16], syn[16], syx[16];
    float mnx = INFINITY, mxx = -INFINITY, mny = INFINITY, mxy = -INFINITY;
    int stride = gridDim.x * blockDim.x;
    for (int i = blockIdx.x * blockDim.x + threadIdx.x; i < n4; i += stride){
        mm4(x[i], mnx, mxx);
        mm4(y[i], mny, mxy);
    }
    #pragma unroll
    for (int off = 32; off > 0; off >>= 1){
        mnx = fminf(mnx, __shfl_down(mnx, off, 64));
        mxx = fmaxf(mxx, __shfl_down(mxx, off, 64));
        mny = fminf(mny, __shfl_down(mny, off, 64));
        mxy = fmaxf(mxy, __shfl_down(mxy, off, 64));
    }
    int t = threadIdx.x;
    if ((t & 63) == 0){
        int w = t >> 6;
        sxn[w] = mnx; sxx[w] = mxx; syn[w] = mny; syx[w] = mxy;
    }
    __syncthreads();
    if (t == 0){
        int nw = blockDim.x >> 6;
        for (int w = 1; w < nw; ++w){
            mnx = fminf(mnx, sxn[w]); mxx = fmaxf(mxx, sxx[w]);
            mny = fminf(mny, syn[w]); mxy = fmaxf(mxy, syx[w]);
        }
        atomicMin(&mm[0], f2key(mnx));
        atomicMax(&mm[1], f2key(mxx));
        atomicMin(&mm[2], f2key(mny));
        atomicMax(&mm[3], f2key(mxy));
    }
}

__global__ void __launch_bounds__(1024)
hist_legacy(const float4* __restrict__ x, const float4* __restrict__ y,
            const uint32_t* __restrict__ mm, uint32_t* __restrict__ hist, int n4){
    __shared__ uint32_t lh[HIST_WORDS8];
    for (int w = threadIdx.x; w < HIST_WORDS8; w += blockDim.x) lh[w] = 0u;
    __syncthreads();
    float mnx = key2f(mm[0]);
    float sx  = 256.0f / ((key2f(mm[1]) - mnx) + 1e-8f);
    float mny = key2f(mm[2]);
    float sy  = 256.0f / ((key2f(mm[3]) - mny) + 1e-8f);
    int stride = gridDim.x * blockDim.x;
    for (int i = blockIdx.x * blockDim.x + threadIdx.x; i < n4; i += stride)
        bin4(x[i], y[i], mnx, sx, mny, sy, lh);
    __syncthreads();
    for (int w = threadIdx.x; w < HIST_WORDS8; w += blockDim.x){
        uint32_t v = lh[w];
        if (v){
            uint32_t c0 = v & 255u, c1 = (v >> 8) & 255u, c2 = (v >> 16) & 255u, c3 = v >> 24;
            if (c0) atomicAdd(&hist[4*w + 0], c0);
            if (c1) atomicAdd(&hist[4*w + 1], c1);
            if (c2) atomicAdd(&hist[4*w + 2], c2);
            if (c3) atomicAdd(&hist[4*w + 3], c3);
        }
    }
}

__global__ void __launch_bounds__(1024)
finalize_kernel(const uint32_t* __restrict__ hist, float* __restrict__ out, int n){
    __shared__ uint32_t rsum[256];
    __shared__ uint32_t csum4[1024];
    __shared__ uint32_t csum[256];
    __shared__ double red[16];
    finalize_dev(hist, out, n, rsum, csum4, csum, red);
}

extern "C" void kernel_launch(void* const* d_in, const int* in_sizes, int n_in,
                              void* d_out, int out_size, void* d_ws, size_t ws_size,
                              hipStream_t stream){
    const float4* x = (const float4*)d_in[0];
    const float4* y = (const float4*)d_in[1];
    float* out = (float*)d_out;
    uint32_t* ws = (uint32_t*)d_ws;

    int n  = in_sizes[0];
    int n4 = n / 4;

    size_t need = ((size_t)HIST_BINS + 1024 + (size_t)NBLK * HIST_WORDS8) * 4;  // ~17 MB
    if (ws_size >= need){
        void* args[] = {(void*)&x, (void*)&y, (void*)&ws, (void*)&out, (void*)&n, (void*)&n4};
        hipLaunchCooperativeKernel((const void*)fused_kernel, dim3(NBLK), dim3(NTHR),
                                   args, 0, stream);
    } else {
        uint32_t* hist = ws;
        uint32_t* mm   = ws + HIST_BINS;
        hipMemsetAsync(hist, 0, HIST_BINS * sizeof(uint32_t), stream);
        init_mm_kernel<<<1, 1, 0, stream>>>(mm);
        minmax_legacy<<<512, 1024, 0, stream>>>(x, y, mm, n4);
        hist_legacy<<<512, 1024, 0, stream>>>(x, y, mm, hist, n4);
        finalize_kernel<<<1, 1024, 0, stream>>>(hist, out, n);
    }
}

// Round 4
// 411.332 us; speedup vs baseline: 1.0972x; 1.0972x over previous
//
#include <hip/hip_runtime.h>
#include <stdint.h>
#include <math.h>

#define HIST_BINS   65536
#define HIST_WORDS8 16384          // uint32 words, 4 packed uint8 bins each (64 KB LDS)
#define NBLK        256            // = CU count; 64.5 KB LDS + 44 VGPR -> 2 blocks/CU
                                   // capacity, so all 256 blocks trivially co-resident
#define NTHR        1024

#define AGENT __HIP_MEMORY_SCOPE_AGENT

// Manual grid barrier (regular launch; cooperative-launch path measured +189 us
// overhead in round 3). Monotone counter, release on arrive, acquire on spin —
// same mechanism CG grid.sync() uses. t0 spins, rest park at s_barrier.
__device__ __forceinline__ void grid_bar(uint32_t* bar, uint32_t target){
    __syncthreads();
    if (threadIdx.x == 0){
        __hip_atomic_fetch_add(bar, 1u, __ATOMIC_ACQ_REL, AGENT);
        while (__hip_atomic_load(bar, __ATOMIC_ACQUIRE, AGENT) < target)
            __builtin_amdgcn_s_sleep(2);
    }
    __syncthreads();
}

// ---------- float <-> monotonic uint key (legacy fallback only) ----------
__device__ __forceinline__ uint32_t f2key(float f){
    uint32_t u = __float_as_uint(f);
    return (u & 0x80000000u) ? ~u : (u | 0x80000000u);
}
__device__ __forceinline__ float key2f(uint32_t k){
    uint32_t u = (k & 0x80000000u) ? (k ^ 0x80000000u) : ~k;
    return __uint_as_float(u);
}

__device__ __forceinline__ void mm4(float4 a, float& mn, float& mx){
    mn = fminf(mn, fminf(fminf(a.x, a.y), fminf(a.z, a.w)));
    mx = fmaxf(mx, fmaxf(fmaxf(a.x, a.y), fmaxf(a.z, a.w)));
}

__device__ __forceinline__ void bin_pair(float vx, float vy,
                                         float mnx, float sx, float mny, float sy,
                                         uint32_t* lh){
    int ix = (int)floorf((vx - mnx) * sx);
    int iy = (int)floorf((vy - mny) * sy);
    ix = ix < 0 ? 0 : (ix > 255 ? 255 : ix);
    iy = iy < 0 ? 0 : (iy > 255 ? 255 : iy);
    uint32_t bin = ((uint32_t)ix << 8) | (uint32_t)iy;
    atomicAdd(&lh[bin >> 2], 1u << ((bin & 3u) * 8u));
}

__device__ __forceinline__ void bin4(float4 a, float4 b,
                                     float mnx, float sx, float mny, float sy,
                                     uint32_t* lh){
    bin_pair(a.x, b.x, mnx, sx, mny, sy, lh);
    bin_pair(a.y, b.y, mnx, sx, mny, sy, lh);
    bin_pair(a.z, b.z, mnx, sx, mny, sy, lh);
    bin_pair(a.w, b.w, mnx, sx, mny, sy, lh);
}

__device__ double bsum1024(double v, double* red, int t){
    #pragma unroll
    for (int off = 32; off > 0; off >>= 1) v += __shfl_down(v, off, 64);
    __syncthreads();
    if ((t & 63) == 0) red[t >> 6] = v;
    __syncthreads();
    if (t == 0){
        double s = 0.0;
        for (int w = 0; w < 16; ++w) s += red[w];
        v = s;
    }
    return v;  // valid in thread 0 only
}

// Shared finalize body (all 1024 threads of the calling block participate).
__device__ void finalize_dev(const uint32_t* __restrict__ hist, float* __restrict__ out,
                             int n, uint32_t* rsum, uint32_t* csum4, uint32_t* csum,
                             double* red){
    int t = threadIdx.x;
    // Phase A: row sums. 4 threads per row, 16 uint4 (64 words) each, coalesced.
    {
        int r = t >> 2, q = t & 3;
        const uint4* hp = (const uint4*)(hist + r * 256 + q * 64);
        uint32_t s = 0;
        #pragma unroll
        for (int k = 0; k < 16; ++k){
            uint4 v = hp[k];
            s += v.x + v.y + v.z + v.w;
        }
        s += __shfl_down(s, 2, 64);
        s += __shfl_down(s, 1, 64);
        if (q == 0) rsum[r] = s;
    }
    // Phase B: col sums. c = t&255 (coalesced across lanes), 4 row-groups.
    {
        int c = t & 255, g = t >> 8;
        const uint32_t* hp = hist + g * 64 * 256 + c;
        uint32_t s = 0;
        #pragma unroll 8
        for (int r = 0; r < 64; ++r) s += hp[r * 256];
        csum4[g * 256 + c] = s;
    }
    __syncthreads();
    if (t < 256) csum[t] = csum4[t] + csum4[256 + t] + csum4[512 + t] + csum4[768 + t];
    __syncthreads();

    const double invn = 1.0 / (double)n;
    const double dn = (double)n;
    double mi = 0.0;
    {
        int c = t & 255, rb = t >> 8;
        double cs = (double)csum[c];
        for (int k = 0; k < 64; ++k){
            int r = k * 4 + rb;
            uint32_t cnt = hist[r * 256 + c];
            if (cnt){
                double rs = (double)rsum[r];
                double ratio = ((double)cnt * dn) / (rs * cs);
                mi += (double)cnt * (double)logf((float)ratio);
            }
        }
        mi *= invn;
    }
    double hx = 0.0, hy = 0.0;
    if (t < 256){
        double px = (double)rsum[t] * invn;
        double py = (double)csum[t] * invn;
        hx = px * log(px + 1e-8);
        hy = py * log(py + 1e-8);
    }
    double mi_s = bsum1024(mi, red, t);
    double hx_s = bsum1024(hx, red, t);
    double hy_s = bsum1024(hy, red, t);
    if (t == 0){
        double h_x = -hx_s, h_y = -hy_s;
        double nmi = mi_s / (sqrt(h_x * h_y) + 1e-8);
        out[0] = (float)(-nmi);
    }
}

// ===================== fused kernel (regular launch, manual barriers) ========
// ws layout (uint32 words):
//   [0 .. 65535]            final uint32 joint histogram (256 KB)
//   [65536 .. 66559]        per-block minmax float4 {mn_x, mx_x, mn_y, mx_y} (4 KB)
//   [66560]                 barrier counter (zeroed by hipMemsetAsync pre-launch)
//   [66624 ...]             256 packed-uint8 partial histograms (16 MB)
__global__ void __launch_bounds__(NTHR, 4)
fused_kernel(const float4* __restrict__ x, const float4* __restrict__ y,
             uint32_t* __restrict__ ws, float* __restrict__ out, int n, int n4){
    union SM {
        uint32_t lh[HIST_WORDS8];       // 64 KB packed-uint8 local histogram
        uint32_t sm[64][16][16];        // 64 KB reduce staging
        struct {
            uint32_t rsum[256];
            uint32_t csum4[1024];
            uint32_t csum[256];
            double   red[16];
        } fin;                          // 6.3 KB finalize
    };
    __shared__ SM s;
    __shared__ float sxn[16], sxx[16], syn[16], syx[16];
    __shared__ float scale_sh[4];
    __shared__ int lastflag;

    uint32_t* hist     = ws;
    float*    blockmm  = (float*)(ws + HIST_BINS);
    uint32_t* bar      = ws + HIST_BINS + 1024;
    uint32_t* partials = ws + HIST_BINS + 1024 + 64;

    int t   = threadIdx.x;
    int bid = blockIdx.x;
    int seg   = (n4 + NBLK - 1) / NBLK;     // 32768 for n4 = 8.39M
    int start = bid * seg;
    int end   = start + seg; if (end > n4) end = n4;

    // ---- phase 1: per-block minmax of this block's x/y segments ----
    float mnx = INFINITY, mxx = -INFINITY, mny = INFINITY, mxy = -INFINITY;
    for (int i = start + t; i < end; i += NTHR){
        float4 a = x[i], b = y[i];
        mm4(a, mnx, mxx);
        mm4(b, mny, mxy);
    }
    #pragma unroll
    for (int off = 32; off > 0; off >>= 1){
        mnx = fminf(mnx, __shfl_down(mnx, off, 64));
        mxx = fmaxf(mxx, __shfl_down(mxx, off, 64));
        mny = fminf(mny, __shfl_down(mny, off, 64));
        mxy = fmaxf(mxy, __shfl_down(mxy, off, 64));
    }
    if ((t & 63) == 0){
        int w = t >> 6;
        sxn[w] = mnx; sxx[w] = mxx; syn[w] = mny; syx[w] = mxy;
    }
    __syncthreads();
    if (t == 0){
        for (int w = 1; w < 16; ++w){
            mnx = fminf(mnx, sxn[w]); mxx = fmaxf(mxx, sxx[w]);
            mny = fminf(mny, syn[w]); mxy = fmaxf(mxy, syx[w]);
        }
        ((float4*)blockmm)[bid] = make_float4(mnx, mxx, mny, mxy);
    }
    grid_bar(bar, NBLK);

    // ---- phase 2: zero LDS hist + compute global scale (redundant per block) ----
    for (int w = t; w < HIST_WORDS8; w += NTHR) s.lh[w] = 0u;
    if (t < NBLK){
        float4 m = ((const float4*)blockmm)[t];
        float a = m.x, b = m.y, c = m.z, d = m.w;
        #pragma unroll
        for (int off = 32; off > 0; off >>= 1){
            a = fminf(a, __shfl_down(a, off, 64));
            b = fmaxf(b, __shfl_down(b, off, 64));
            c = fminf(c, __shfl_down(c, off, 64));
            d = fmaxf(d, __shfl_down(d, off, 64));
        }
        if ((t & 63) == 0){
            int w = t >> 6;
            sxn[w] = a; sxx[w] = b; syn[w] = c; syx[w] = d;
        }
    }
    __syncthreads();
    if (t == 0){
        float a = sxn[0], b = sxx[0], c = syn[0], d = syx[0];
        for (int w = 1; w < 4; ++w){
            a = fminf(a, sxn[w]); b = fmaxf(b, sxx[w]);
            c = fminf(c, syn[w]); d = fmaxf(d, syx[w]);
        }
        scale_sh[0] = a;
        scale_sh[1] = 256.0f / ((b - a) + 1e-8f);
        scale_sh[2] = c;
        scale_sh[3] = 256.0f / ((d - c) + 1e-8f);
    }
    __syncthreads();

    // ---- phase 3: LDS histogram over this block's segment ----
    {
        float gmnx = scale_sh[0], gsx = scale_sh[1];
        float gmny = scale_sh[2], gsy = scale_sh[3];
        int base = start;
        for (; base + 4 * NTHR <= end; base += 4 * NTHR){
            int i0 = base + t;
            float4 a0 = x[i0], a1 = x[i0 + NTHR], a2 = x[i0 + 2*NTHR], a3 = x[i0 + 3*NTHR];
            float4 b0 = y[i0], b1 = y[i0 + NTHR], b2 = y[i0 + 2*NTHR], b3 = y[i0 + 3*NTHR];
            bin4(a0, b0, gmnx, gsx, gmny, gsy, s.lh);
            bin4(a1, b1, gmnx, gsx, gmny, gsy, s.lh);
            bin4(a2, b2, gmnx, gsx, gmny, gsy, s.lh);
            bin4(a3, b3, gmnx, gsx, gmny, gsy, s.lh);
        }
        for (int i = base + t; i < end; i += NTHR){
            float4 a = x[i], b = y[i];
            bin4(a, b, gmnx, gsx, gmny, gsy, s.lh);
        }
    }
    __syncthreads();
    {
        uint32_t* part = partials + (size_t)bid * HIST_WORDS8;
        for (int w = t; w < HIST_WORDS8; w += NTHR) part[w] = s.lh[w];
    }
    grid_bar(bar, 2 * NBLK);

    // ---- phase 4: distributed reduce (block b owns word-quads [b*16, b*16+16)) ----
    {
        int ql = t & 15, g = t >> 4;          // 64 groups of 4 partials each
        uint32_t c[16];
        #pragma unroll
        for (int k = 0; k < 16; ++k) c[k] = 0;
        const uint4* basep = (const uint4*)partials;
        size_t qoff = (size_t)bid * 16 + ql;
        #pragma unroll
        for (int j = 0; j < 4; ++j){
            uint4 v = basep[(size_t)(g * 4 + j) * (HIST_WORDS8 / 4) + qoff];
            c[ 0] += v.x & 255u; c[ 1] += (v.x >> 8) & 255u; c[ 2] += (v.x >> 16) & 255u; c[ 3] += v.x >> 24;
            c[ 4] += v.y & 255u; c[ 5] += (v.y >> 8) & 255u; c[ 6] += (v.y >> 16) & 255u; c[ 7] += v.y >> 24;
            c[ 8] += v.z & 255u; c[ 9] += (v.z >> 8) & 255u; c[10] += (v.z >> 16) & 255u; c[11] += v.z >> 24;
            c[12] += v.w & 255u; c[13] += (v.w >> 8) & 255u; c[14] += (v.w >> 16) & 255u; c[15] += v.w >> 24;
        }
        #pragma unroll
        for (int k = 0; k < 16; ++k) s.sm[g][k][ql] = c[k];
        __syncthreads();
        if (t < 256){
            int q2 = t & 15, k = t >> 4;
            uint32_t sum = 0;
            #pragma unroll 8
            for (int gg = 0; gg < 64; ++gg) sum += s.sm[gg][k][q2];
            hist[((size_t)bid * 16 + q2) * 16 + k] = sum;
        }
    }

    // ---- phase 5: last block to arrive does finalize (replaces 3rd barrier) ----
    __syncthreads();
    if (t == 0){
        uint32_t a = __hip_atomic_fetch_add(bar, 1u, __ATOMIC_ACQ_REL, AGENT);
        lastflag = (a == 3u * NBLK - 1u);
    }
    __syncthreads();
    if (lastflag)
        finalize_dev(hist, out, n, s.fin.rsum, s.fin.csum4, s.fin.csum, s.fin.red);
}

// ===================== legacy fallback (small workspace) =====================
__global__ void init_mm_kernel(uint32_t* __restrict__ mm){
    mm[0] = 0xFFFFFFFFu; mm[1] = 0u; mm[2] = 0xFFFFFFFFu; mm[3] = 0u;
}

__global__ void __launch_bounds__(1024)
minmax_legacy(const float4* __restrict__ x, const float4* __restrict__ y,
              uint32_t* __restrict__ mm, int n4){
    __shared__ float sxn[16], sxx[16], syn[16], syx[16];
    float mnx = INFINITY, mxx = -INFINITY, mny = INFINITY, mxy = -INFINITY;
    int stride = gridDim.x * blockDim.x;
    for (int i = blockIdx.x * blockDim.x + threadIdx.x; i < n4; i += stride){
        mm4(x[i], mnx, mxx);
        mm4(y[i], mny, mxy);
    }
    #pragma unroll
    for (int off = 32; off > 0; off >>= 1){
        mnx = fminf(mnx, __shfl_down(mnx, off, 64));
        mxx = fmaxf(mxx, __shfl_down(mxx, off, 64));
        mny = fminf(mny, __shfl_down(mny, off, 64));
        mxy = fmaxf(mxy, __shfl_down(mxy, off, 64));
    }
    int t = threadIdx.x;
    if ((t & 63) == 0){
        int w = t >> 6;
        sxn[w] = mnx; sxx[w] = mxx; syn[w] = mny; syx[w] = mxy;
    }
    __syncthreads();
    if (t == 0){
        int nw = blockDim.x >> 6;
        for (int w = 1; w < nw; ++w){
            mnx = fminf(mnx, sxn[w]); mxx = fmaxf(mxx, sxx[w]);
            mny = fminf(mny, syn[w]); mxy = fmaxf(mxy, syx[w]);
        }
        atomicMin(&mm[0], f2key(mnx));
        atomicMax(&mm[1], f2key(mxx));
        atomicMin(&mm[2], f2key(mny));
        atomicMax(&mm[3], f2key(mxy));
    }
}

__global__ void __launch_bounds__(1024)
hist_legacy(const float4* __restrict__ x, const float4* __restrict__ y,
            const uint32_t* __restrict__ mm, uint32_t* __restrict__ hist, int n4){
    __shared__ uint32_t lh[HIST_WORDS8];
    for (int w = threadIdx.x; w < HIST_WORDS8; w += blockDim.x) lh[w] = 0u;
    __syncthreads();
    float mnx = key2f(mm[0]);
    float sx  = 256.0f / ((key2f(mm[1]) - mnx) + 1e-8f);
    float mny = key2f(mm[2]);
    float sy  = 256.0f / ((key2f(mm[3]) - mny) + 1e-8f);
    int stride = gridDim.x * blockDim.x;
    for (int i = blockIdx.x * blockDim.x + threadIdx.x; i < n4; i += stride)
        bin4(x[i], y[i], mnx, sx, mny, sy, lh);
    __syncthreads();
    for (int w = threadIdx.x; w < HIST_WORDS8; w += blockDim.x){
        uint32_t v = lh[w];
        if (v){
            uint32_t c0 = v & 255u, c1 = (v >> 8) & 255u, c2 = (v >> 16) & 255u, c3 = v >> 24;
            if (c0) atomicAdd(&hist[4*w + 0], c0);
            if (c1) atomicAdd(&hist[4*w + 1], c1);
            if (c2) atomicAdd(&hist[4*w + 2], c2);
            if (c3) atomicAdd(&hist[4*w + 3], c3);
        }
    }
}

__global__ void __launch_bounds__(1024)
finalize_kernel(const uint32_t* __restrict__ hist, float* __restrict__ out, int n){
    __shared__ uint32_t rsum[256];
    __shared__ uint32_t csum4[1024];
    __shared__ uint32_t csum[256];
    __shared__ double red[16];
    finalize_dev(hist, out, n, rsum, csum4, csum, red);
}

extern "C" void kernel_launch(void* const* d_in, const int* in_sizes, int n_in,
                              void* d_out, int out_size, void* d_ws, size_t ws_size,
                              hipStream_t stream){
    const float4* x = (const float4*)d_in[0];
    const float4* y = (const float4*)d_in[1];
    float* out = (float*)d_out;
    uint32_t* ws = (uint32_t*)d_ws;

    int n  = in_sizes[0];
    int n4 = n / 4;

    size_t need = ((size_t)HIST_BINS + 1024 + 64 + (size_t)NBLK * HIST_WORDS8) * 4;  // ~17 MB
    if (ws_size >= need){
        uint32_t* bar = ws + HIST_BINS + 1024;
        hipMemsetAsync(bar, 0, sizeof(uint32_t), stream);
        fused_kernel<<<NBLK, NTHR, 0, stream>>>(x, y, ws, out, n, n4);
    } else {
        uint32_t* hist = ws;
        uint32_t* mm   = ws + HIST_BINS;
        hipMemsetAsync(hist, 0, HIST_BINS * sizeof(uint32_t), stream);
        init_mm_kernel<<<1, 1, 0, stream>>>(mm);
        minmax_legacy<<<512, 1024, 0, stream>>>(x, y, mm, n4);
        hist_legacy<<<512, 1024, 0, stream>>>(x, y, mm, hist, n4);
        finalize_kernel<<<1, 1024, 0, stream>>>(hist, out, n);
    }
}